// Round 4
// baseline (275126.514 us; speedup 1.0000x reference)
//
#include <hip/hip_runtime.h>
#include <hip/hip_bf16.h>

#define NMEL 80

__device__ __forceinline__ float bf2f(unsigned short u) {
  unsigned v = ((unsigned)u) << 16; float f; __builtin_memcpy(&f, &v, 4); return f;
}
__device__ __forceinline__ unsigned short f2bf_u(float f) {
  __hip_bfloat16 h = __float2bfloat16(f); unsigned short u; __builtin_memcpy(&u, &h, 2); return u;
}
__device__ __forceinline__ float agload(const float* p) {
  return __hip_atomic_load(p, __ATOMIC_RELAXED, __HIP_MEMORY_SCOPE_AGENT);
}
__device__ __forceinline__ void agstore(float* p, float v) {
  __hip_atomic_store(p, v, __ATOMIC_RELAXED, __HIP_MEMORY_SCOPE_AGENT);
}
__device__ __forceinline__ void unpk(unsigned u, float& lo, float& hi) {
  unsigned l = u << 16, h = u & 0xffff0000u;
  __builtin_memcpy(&lo, &l, 4); __builtin_memcpy(&hi, &h, 4);
}
struct F8 { float a0, a1, a2, a3, a4, a5, a6, a7; };
__device__ __forceinline__ F8 unpk8(uint4 u) {
  F8 r;
  unpk(u.x, r.a0, r.a1); unpk(u.y, r.a2, r.a3);
  unpk(u.z, r.a4, r.a5); unpk(u.w, r.a6, r.a7);
  return r;
}

// ---------------- workspace layout (bytes) ----------------
// attn8 bf16 [b][a>>3][te][a&7], pre-scaled by 2*log2(e)
constexpr size_t OFF_ATTN8 = 0;
constexpr size_t SZ_ATTN8 = (size_t)64 * 256 * 1024 * 2;           // 33,554,432
constexpr size_t OFF_PRE2 = OFF_ATTN8 + SZ_ATTN8;                  // bf16 [64000][256]
constexpr size_t SZ_PRE2 = (size_t)64000 * 256 * 2;
constexpr size_t OFF_WG4 = OFF_PRE2 + SZ_PRE2;                     // f32 [4][64][256][4]
constexpr size_t SZ_W4 = (size_t)262144 * 4;                       // 1 MiB each
constexpr size_t OFF_WP4 = OFF_WG4 + SZ_W4;
constexpr size_t OFF_WHH4 = OFF_WP4 + SZ_W4;                       // f32 [4][16][1024][4]
constexpr size_t OFF_WDEC4 = OFF_WHH4 + SZ_W4;                     // f32 [4][16][256][4]
constexpr size_t SZ_WDEC4 = (size_t)65536 * 4;
constexpr size_t OFF_MELT = OFF_WDEC4 + SZ_WDEC4;                  // f32 [4][128][80]
constexpr size_t SZ_MELT = (size_t)4 * 128 * 80 * 4;
constexpr size_t OFF_STOPT = OFF_MELT + SZ_MELT;                   // f32 [4][128]
constexpr size_t SZ_STOPT = (size_t)4 * 128 * 4;
constexpr size_t OFF_BIASG = OFF_STOPT + SZ_STOPT;                 // f32 [4][256]
constexpr size_t SZ_BIASG = (size_t)4 * 256 * 4;
constexpr size_t OFF_EXCH = (OFF_BIASG + SZ_BIASG + 255) & ~(size_t)255;
// exchange region (float indices)
constexpr size_t EXF_DEC = 0;                          // [2][64][4][256]
constexpr size_t EXN_DEC = (size_t)2 * 64 * 4 * 256;
constexpr size_t EXF_GH = EXF_DEC + EXN_DEC;           // [2][64][4][1024]
constexpr size_t EXN_GH = (size_t)2 * 64 * 4 * 1024;
constexpr size_t EXF_CTX = EXF_GH + EXN_GH;            // [64][4][256]
constexpr size_t EXN_CTX = (size_t)64 * 4 * 256;
constexpr size_t EXF_S = EXF_CTX + EXN_CTX;            // [64][16]
constexpr size_t EXN_S = 64 * 16;
constexpr size_t EXF_CTR = EXF_S + EXN_S;              // u32 [64][16]
constexpr size_t EXN_CTR = 64 * 16;
constexpr size_t EXCH_FLOATS = EXF_CTR + EXN_CTR;
constexpr size_t SZ_EXCH = EXCH_FLOATS * 4;
constexpr size_t WS_NEED = OFF_EXCH + SZ_EXCH;         // ~72.8 MiB

// ---------------- weight re-layout (fp32 packed-4) ----------------
__global__ __launch_bounds__(256) void prep_weights(
    const float* __restrict__ W_ih, const float* __restrict__ W_hh,
    const float* __restrict__ W_dec, const float* __restrict__ mel_W,
    const float* __restrict__ stop_W, const float* __restrict__ b_ih,
    const float* __restrict__ b_hh,
    float* __restrict__ Wg4, float* __restrict__ Wp4,
    float* __restrict__ Whh4, float* __restrict__ Wdec4,
    float* __restrict__ MelT, float* __restrict__ StopT, float* __restrict__ biasG) {
  int idx = blockIdx.x * 256 + threadIdx.x;
  if (idx < 262144) {
    // Wg4[s][kq][r][q] = W_ih[grow(r,s)][256 + kq*4+q]; Wp4 same with col kq*4+q
    int q = idx & 3, r = (idx >> 2) & 255, kq = (idx >> 10) & 63, s = idx >> 16;
    int grow = ((r >> 6) << 8) + s * 64 + (r & 63);
    Wg4[idx] = W_ih[(size_t)grow * 512 + 256 + kq * 4 + q];
    Wp4[idx] = W_ih[(size_t)grow * 512 + kq * 4 + q];
  } else if (idx < 524288) {
    // Whh4[s][hq][rr][q] = W_hh[rr][s*64 + hq*4 + q]
    int i = idx - 262144;
    int q = i & 3, rr = (i >> 2) & 1023, hq = (i >> 12) & 15, s = i >> 16;
    Whh4[i] = W_hh[(size_t)rr * 256 + s * 64 + hq * 4 + q];
  } else if (idx < 589824) {
    // Wdec4[s][hq][a][q] = W_dec[a][s*64 + hq*4 + q]
    int i = idx - 524288;
    int q = i & 3, a = (i >> 2) & 255, hq = (i >> 10) & 15, s = (i >> 14) & 3;
    Wdec4[i] = W_dec[(size_t)a * 256 + s * 64 + hq * 4 + q];
  } else if (idx < 589824 + 40960) {
    int k = idx - 589824;
    int m = k % 80, r = k / 80;
    int cc = r & 127, s = r >> 7;
    int col = (cc < 64) ? (s * 64 + cc) : (256 + s * 64 + (cc - 64));
    MelT[k] = mel_W[(size_t)m * 512 + col];
  } else if (idx < 589824 + 40960 + 512) {
    int k = idx - (589824 + 40960);
    int cc = k & 127, s = k >> 7;
    int col = (cc < 64) ? (s * 64 + cc) : (256 + s * 64 + (cc - 64));
    StopT[k] = stop_W[col];
  } else if (idx < 589824 + 40960 + 512 + 1024) {
    int k = idx - (589824 + 40960 + 512);
    int j = k & 255, s = k >> 8;
    int row = ((j >> 6) << 8) + s * 64 + (j & 63);
    biasG[k] = b_ih[row] + b_hh[row];
  }
}

// ---------------- attn_enc GEMM -> bf16 packed attn8 (pre-scaled by 2*log2e) ----------------
__global__ __launch_bounds__(256) void attn_gemm(const float* __restrict__ enc,
                                                 const float* __restrict__ W_enc,
                                                 const float* __restrict__ b_enc,
                                                 unsigned short* __restrict__ attn8) {
  __shared__ unsigned short Alds[64 * 260];
  const int tid = threadIdx.x;
  const int row0 = blockIdx.x * 64;
  const int wv = tid >> 6, lane = tid & 63, nb = wv * 64;
  for (int idx = tid; idx < 64 * 256; idx += 256) {
    int r = idx >> 8, k = idx & 255;
    Alds[r * 260 + k] = f2bf_u(enc[(size_t)(row0 + r) * 256 + k]);
  }
  __syncthreads();
  float acc[64];
#pragma unroll
  for (int n = 0; n < 64; ++n) acc[n] = b_enc[nb + n];
  for (int k8 = 0; k8 < 256; k8 += 8) {
    ushort4 ua = *(const ushort4*)&Alds[lane * 260 + k8];
    ushort4 ub = *(const ushort4*)&Alds[lane * 260 + k8 + 4];
    float a0 = bf2f(ua.x), a1 = bf2f(ua.y), a2 = bf2f(ua.z), a3 = bf2f(ua.w);
    float a4 = bf2f(ub.x), a5 = bf2f(ub.y), a6 = bf2f(ub.z), a7 = bf2f(ub.w);
#pragma unroll
    for (int n = 0; n < 64; ++n) {
      const float4* wp = (const float4*)(W_enc + (size_t)(nb + n) * 256 + k8);
      float4 w0 = wp[0], w1 = wp[1];
      acc[n] = fmaf(a0, w0.x, acc[n]); acc[n] = fmaf(a1, w0.y, acc[n]);
      acc[n] = fmaf(a2, w0.z, acc[n]); acc[n] = fmaf(a3, w0.w, acc[n]);
      acc[n] = fmaf(a4, w1.x, acc[n]); acc[n] = fmaf(a5, w1.y, acc[n]);
      acc[n] = fmaf(a6, w1.z, acc[n]); acc[n] = fmaf(a7, w1.w, acc[n]);
    }
  }
  const float CE = 2.8853900817779268f;  // 2*log2(e)
  const int b = row0 >> 10;
  const int te = (row0 & 1023) + lane;
#pragma unroll
  for (int n = 0; n < 64; n += 2) {
    int a0i = nb + n;
    unsigned pair = (unsigned)f2bf_u(acc[n] * CE) | ((unsigned)f2bf_u(acc[n + 1] * CE) << 16);
    size_t elem = (((size_t)b) << 18) + (((size_t)(a0i >> 3)) << 13) + (((size_t)te) << 3) +
                  (a0i & 7);
    *(unsigned*)(attn8 + elem) = pair;
  }
}

// ---------------- fused prenet: pre2 = relu(relu(prev@W1^T+b1)@W2^T+b2), bf16 out ----------------
__global__ __launch_bounds__(256) void prenet_fused(const float* __restrict__ tmel,
                                                    const float* __restrict__ W1,
                                                    const float* __restrict__ b1,
                                                    const float* __restrict__ W2,
                                                    const float* __restrict__ b2,
                                                    unsigned short* __restrict__ pre2) {
  __shared__ unsigned short Alds[64 * 260];
  const int tid = threadIdx.x;
  const int row0 = blockIdx.x * 64;
  const int wv = tid >> 6, lane = tid & 63, nb = wv * 64;
  for (int idx = tid; idx < 64 * 80; idx += 256) {
    int r = idx / 80, k = idx - r * 80;
    int R = row0 + r;
    float v = (R % 1000 != 0) ? tmel[(size_t)(R - 1) * NMEL + k] : 0.f;
    Alds[r * 260 + k] = f2bf_u(v);
  }
  __syncthreads();
  float acc[64];
#pragma unroll
  for (int n = 0; n < 64; ++n) acc[n] = b1[nb + n];
  for (int k8 = 0; k8 < 80; k8 += 8) {
    ushort4 ua = *(const ushort4*)&Alds[lane * 260 + k8];
    ushort4 ub = *(const ushort4*)&Alds[lane * 260 + k8 + 4];
    float a0 = bf2f(ua.x), a1 = bf2f(ua.y), a2 = bf2f(ua.z), a3 = bf2f(ua.w);
    float a4 = bf2f(ub.x), a5 = bf2f(ub.y), a6 = bf2f(ub.z), a7 = bf2f(ub.w);
#pragma unroll
    for (int n = 0; n < 64; ++n) {
      const float4* wp = (const float4*)(W1 + (size_t)(nb + n) * 80 + k8);
      float4 w0 = wp[0], w1 = wp[1];
      acc[n] = fmaf(a0, w0.x, acc[n]); acc[n] = fmaf(a1, w0.y, acc[n]);
      acc[n] = fmaf(a2, w0.z, acc[n]); acc[n] = fmaf(a3, w0.w, acc[n]);
      acc[n] = fmaf(a4, w1.x, acc[n]); acc[n] = fmaf(a5, w1.y, acc[n]);
      acc[n] = fmaf(a6, w1.z, acc[n]); acc[n] = fmaf(a7, w1.w, acc[n]);
    }
  }
  __syncthreads();
#pragma unroll
  for (int n = 0; n < 64; ++n) Alds[lane * 260 + nb + n] = f2bf_u(fmaxf(acc[n], 0.f));
  __syncthreads();
#pragma unroll
  for (int n = 0; n < 64; ++n) acc[n] = b2[nb + n];
  for (int k8 = 0; k8 < 256; k8 += 8) {
    ushort4 ua = *(const ushort4*)&Alds[lane * 260 + k8];
    ushort4 ub = *(const ushort4*)&Alds[lane * 260 + k8 + 4];
    float a0 = bf2f(ua.x), a1 = bf2f(ua.y), a2 = bf2f(ua.z), a3 = bf2f(ua.w);
    float a4 = bf2f(ub.x), a5 = bf2f(ub.y), a6 = bf2f(ub.z), a7 = bf2f(ub.w);
#pragma unroll
    for (int n = 0; n < 64; ++n) {
      const float4* wp = (const float4*)(W2 + (size_t)(nb + n) * 256 + k8);
      float4 w0 = wp[0], w1 = wp[1];
      acc[n] = fmaf(a0, w0.x, acc[n]); acc[n] = fmaf(a1, w0.y, acc[n]);
      acc[n] = fmaf(a2, w0.z, acc[n]); acc[n] = fmaf(a3, w0.w, acc[n]);
      acc[n] = fmaf(a4, w1.x, acc[n]); acc[n] = fmaf(a5, w1.y, acc[n]);
      acc[n] = fmaf(a6, w1.z, acc[n]); acc[n] = fmaf(a7, w1.w, acc[n]);
    }
  }
  __syncthreads();
#pragma unroll
  for (int n = 0; n < 64; ++n) Alds[lane * 260 + nb + n] = f2bf_u(fmaxf(acc[n], 0.f));
  __syncthreads();
  for (int idx = tid; idx < 64 * 128; idx += 256) {
    int r = idx >> 7, k2 = (idx & 127) * 2;
    unsigned pair = (unsigned)Alds[r * 260 + k2] | ((unsigned)Alds[r * 260 + k2 + 1] << 16);
    *(unsigned*)(pre2 + (size_t)(row0 + r) * 256 + k2) = pair;
  }
}

// ---------------- persistent decoder loop: 256 WGs x 1024 threads ----------------
// b = wg&63, s = wg>>6 (slices of one b share wg%8 -> same XCD under round-robin).
__global__ __launch_bounds__(1024) void decoder_loop(
    const unsigned short* __restrict__ attn8, const float* __restrict__ enc,
    const unsigned short* __restrict__ pre2,
    const float* __restrict__ Wg4, const float* __restrict__ Wp4,
    const float* __restrict__ Whh4, const float* __restrict__ Wdec4,
    const float* __restrict__ MelT, const float* __restrict__ StopT,
    const float* __restrict__ biasG,
    float* exch, unsigned* ctr,
    const float* __restrict__ b_dec, const float* __restrict__ v_w,
    const float* __restrict__ v_b, const float* __restrict__ enc_mask,
    const float* __restrict__ mel_b, const float* __restrict__ stop_b,
    float* out) {
  __shared__ __align__(16) float dec_lds[256];
  __shared__ __align__(16) float v2_lds[256];
  __shared__ __align__(16) float p_lds[256];
  __shared__ __align__(16) float ctx_lds[256];
  __shared__ __align__(16) float pre_lds[256];
  __shared__ float gates_lds[256];
  __shared__ __align__(16) float tmp_lds[1024];
  __shared__ __align__(16) float ctxp_lds[32 * 256];
  __shared__ float gpart_lds[1024];
  __shared__ float dpart_lds[1024];
  __shared__ float c_lds[64], h_lds[64];
  __shared__ float red_lds[16];
  __shared__ float stop_lds[128];
  __shared__ float sv_lds;

  const int tid = threadIdx.x;
  const int b = blockIdx.x & 63, s = blockIdx.x >> 6;
  const int t8 = tid & 255;
  const int chunk = tid >> 8;
  const int lane = tid & 63, wid = tid >> 6;
  const float CE = 2.8853900817779268f;   // 2*log2(e)
  const float L2E = 1.4426950408889634f;  // log2(e)

  if (tid < 256) {
    v2_lds[tid] = -2.f * v_w[tid];
    if (tid < 64) c_lds[tid] = 0.f;
  }
  if (tid == 0) {
    float sv = 0.f;
    for (int k = 0; k < 256; ++k) sv += v_w[k];
    sv_lds = sv;
  }
  __syncthreads();
  const float Sv = sv_lds;
  const float vb = v_b[0];
  const float maskv = (tid < 256) ? enc_mask[b * 1024 + s * 256 + tid] : 0.f;
  const float bdec_r = (tid < 256) ? b_dec[tid] : 0.f;
  const float biasg_r = (tid < 256) ? biasG[s * 256 + tid] : 0.f;

  const uint4* ap = (const uint4*)attn8 + (((size_t)b) << 15) +
                    (((size_t)(chunk * 8)) << 10) + (s * 256 + t8);
  const int tg = tid >> 5, dl = tid & 31;
  const float* ep = enc + ((size_t)(b * 1024 + s * 256 + tg * 8)) * 256 + dl * 8;
  const float4* wg4 = (const float4*)Wg4 + ((size_t)(s * 64 + chunk * 16)) * 256 + t8;
  const float4* wp4 = (const float4*)Wp4 + ((size_t)(s * 64 + chunk * 16)) * 256 + t8;
  const int grow = ((t8 >> 6) << 8) + s * 64 + (t8 & 63);
  const float4* wh4 = (const float4*)Whh4 + ((size_t)s) * 16384 + tid;
  const float4* wd4 = (const float4*)Wdec4 + ((size_t)(s * 16 + chunk * 4)) * 256 + t8;
  const unsigned short* pre2_b = pre2 + (size_t)b * 256000;

  float* decP = exch + EXF_DEC;
  float* ghP = exch + EXF_GH;
  float* ctxP = exch + EXF_CTX;
  float* sP = exch + EXF_S;
  unsigned* ctrb = ctr + b * 16;
  unsigned epoch = 0;

  for (int it = 0; it < 1000; ++it) {
    const int par = it & 1;
    const int pn = par ^ 1;
    float prefv = (tid < 256) ? bf2f(pre2_b[it * 256 + tid]) : 0.f;
    // ---- A0: gather decP partials (1 coalesced load / thread) ----
    tmp_lds[tid] = agload(decP + ((size_t)(par * 64 + b)) * 1024 + tid);
    __syncthreads();
    if (tid < 256)
      dec_lds[tid] = (bdec_r + tmp_lds[tid] + tmp_lds[256 + tid] + tmp_lds[512 + tid] +
                      tmp_lds[768 + tid]) * CE;
    __syncthreads();
    // ---- A1: energy partial over own 64-a chunk (attn8 bf16) ----
    float acc = 0.f;
#pragma unroll
    for (int i = 0; i < 8; ++i) {
      uint4 u = ap[(size_t)i << 10];
      int ab = chunk * 64 + i * 8;
      float4 d0 = *(const float4*)&dec_lds[ab];
      float4 d1 = *(const float4*)&dec_lds[ab + 4];
      float4 v0 = *(const float4*)&v2_lds[ab];
      float4 v1 = *(const float4*)&v2_lds[ab + 4];
      F8 t = unpk8(u);
      acc = fmaf(v0.x, __builtin_amdgcn_rcpf(1.f + __builtin_amdgcn_exp2f(t.a0 + d0.x)), acc);
      acc = fmaf(v0.y, __builtin_amdgcn_rcpf(1.f + __builtin_amdgcn_exp2f(t.a1 + d0.y)), acc);
      acc = fmaf(v0.z, __builtin_amdgcn_rcpf(1.f + __builtin_amdgcn_exp2f(t.a2 + d0.z)), acc);
      acc = fmaf(v0.w, __builtin_amdgcn_rcpf(1.f + __builtin_amdgcn_exp2f(t.a3 + d0.w)), acc);
      acc = fmaf(v1.x, __builtin_amdgcn_rcpf(1.f + __builtin_amdgcn_exp2f(t.a4 + d1.x)), acc);
      acc = fmaf(v1.y, __builtin_amdgcn_rcpf(1.f + __builtin_amdgcn_exp2f(t.a5 + d1.y)), acc);
      acc = fmaf(v1.z, __builtin_amdgcn_rcpf(1.f + __builtin_amdgcn_exp2f(t.a6 + d1.z)), acc);
      acc = fmaf(v1.w, __builtin_amdgcn_rcpf(1.f + __builtin_amdgcn_exp2f(t.a7 + d1.w)), acc);
    }
    tmp_lds[tid] = acc;
    __syncthreads();
    // ---- A2: softmax numerator + slice sum ----
    if (tid < 256) {
      float e = Sv + vb + tmp_lds[t8] + tmp_lds[256 + t8] + tmp_lds[512 + t8] + tmp_lds[768 + t8];
      float p = (maskv != 0.f) ? __builtin_amdgcn_exp2f(e * L2E) : 0.f;
      p_lds[t8] = p;
      float sp = p;
      for (int m = 32; m; m >>= 1) sp += __shfl_xor(sp, m);
      if (lane == 0) red_lds[wid] = sp;
    }
    __syncthreads();
    // ---- B: context partials (8 te x 8 d per thread, enc fp32) ----
    {
      float c0 = 0, c1 = 0, c2 = 0, c3 = 0, c4 = 0, c5 = 0, c6 = 0, c7 = 0;
#pragma unroll
      for (int j = 0; j < 8; ++j) {
        const float4* er = (const float4*)(ep + (size_t)j * 256);
        float4 e0 = er[0], e1 = er[1];
        float pv = p_lds[tg * 8 + j];
        c0 = fmaf(pv, e0.x, c0); c1 = fmaf(pv, e0.y, c1);
        c2 = fmaf(pv, e0.z, c2); c3 = fmaf(pv, e0.w, c3);
        c4 = fmaf(pv, e1.x, c4); c5 = fmaf(pv, e1.y, c5);
        c6 = fmaf(pv, e1.z, c6); c7 = fmaf(pv, e1.w, c7);
      }
      float* cb = &ctxp_lds[tg * 256 + dl * 8];
      cb[0] = c0; cb[1] = c1; cb[2] = c2; cb[3] = c3;
      cb[4] = c4; cb[5] = c5; cb[6] = c6; cb[7] = c7;
    }
    __syncthreads();
    // ---- B2: reduce 32 -> 4 -> 1 and publish ----
    {
      float scc = 0.f;
#pragma unroll
      for (int j = 0; j < 8; ++j) scc += ctxp_lds[(chunk * 8 + j) * 256 + t8];
      if (tid < 256) pre_lds[tid] = prefv;
      __syncthreads();
      tmp_lds[tid] = scc;
      __syncthreads();
    }
    if (tid < 256) {
      float cp = tmp_lds[t8] + tmp_lds[256 + t8] + tmp_lds[512 + t8] + tmp_lds[768 + t8];
      agstore(ctxP + ((size_t)b * 4 + s) * 256 + t8, cp);
    }
    if (tid == 0)
      agstore(sP + b * 16 + s, red_lds[0] + red_lds[1] + red_lds[2] + red_lds[3]);
    // ================= barrier 1 =================
    __threadfence();
    __syncthreads();
    if (tid == 0) {
      ++epoch;
      __hip_atomic_fetch_add(ctrb, 1u, __ATOMIC_RELEASE, __HIP_MEMORY_SCOPE_AGENT);
      while (__hip_atomic_load(ctrb, __ATOMIC_ACQUIRE, __HIP_MEMORY_SCOPE_AGENT) < 4u * epoch)
        __builtin_amdgcn_s_sleep(1);
    }
    __syncthreads();
    // ---- C: final normalized context ----
    tmp_lds[tid] = agload(ctxP + ((size_t)b * 4 + chunk) * 256 + t8);
    if (tid < 4) red_lds[8 + tid] = agload(sP + b * 16 + tid);
    __syncthreads();
    if (tid < 256) {
      float rS = 1.f / (red_lds[8] + red_lds[9] + red_lds[10] + red_lds[11]);
      ctx_lds[t8] = (tmp_lds[t8] + tmp_lds[256 + t8] + tmp_lds[512 + t8] + tmp_lds[768 + t8]) * rS;
    }
    __syncthreads();
    // ---- D: gate partials (row t8, k-chunk of 64) ----
    {
      float g = agload(ghP + ((size_t)(par * 64 + b)) * 4096 + chunk * 1024 + grow);
#pragma unroll
      for (int i = 0; i < 16; ++i) {
        float4 w = wg4[(size_t)i << 8];
        float4 q = wp4[(size_t)i << 8];
        int kb = chunk * 64 + i * 4;
        float4 x = *(const float4*)&ctx_lds[kb];
        float4 y = *(const float4*)&pre_lds[kb];
        g = fmaf(w.x, x.x, g); g = fmaf(w.y, x.y, g);
        g = fmaf(w.z, x.z, g); g = fmaf(w.w, x.w, g);
        g = fmaf(q.x, y.x, g); g = fmaf(q.y, y.y, g);
        g = fmaf(q.z, y.z, g); g = fmaf(q.w, y.w, g);
      }
      gpart_lds[tid] = g;
    }
    __syncthreads();
    if (tid < 256)
      gates_lds[t8] = biasg_r + gpart_lds[t8] + gpart_lds[256 + t8] + gpart_lds[512 + t8] +
                      gpart_lds[768 + t8];
    __syncthreads();
    // ---- E: LSTM pointwise for own 64 units ----
    if (tid < 64) {
      float ii = gates_lds[tid], ff = gates_lds[64 + tid];
      float gg = gates_lds[128 + tid], oo = gates_lds[192 + tid];
      float c = c_lds[tid];
      float si = __builtin_amdgcn_rcpf(1.f + __builtin_amdgcn_exp2f(-ii * L2E));
      float sf = __builtin_amdgcn_rcpf(1.f + __builtin_amdgcn_exp2f(-ff * L2E));
      float so = __builtin_amdgcn_rcpf(1.f + __builtin_amdgcn_exp2f(-oo * L2E));
      float tg2 = 1.f - 2.f * __builtin_amdgcn_rcpf(1.f + __builtin_amdgcn_exp2f(gg * CE));
      float cn = sf * c + si * tg2;
      float tc = 1.f - 2.f * __builtin_amdgcn_rcpf(1.f + __builtin_amdgcn_exp2f(cn * CE));
      c_lds[tid] = cn;
      h_lds[tid] = so * tc;
    }
    __syncthreads();
    // ---- F: heads ----
    if (tid >= 128 && tid < 256) {
      int cc = tid - 128;
      float xv = (cc < 64) ? h_lds[cc] : ctx_lds[s * 64 + (cc - 64)];
      stop_lds[cc] = StopT[s * 128 + cc] * xv;
    }
    if (tid < 80) {
      float a = (s == 0) ? mel_b[tid] : 0.f;
      const float* mp = MelT + (size_t)s * 10240 + tid;
#pragma unroll 8
      for (int cc = 0; cc < 128; ++cc) {
        float xv = (cc < 64) ? h_lds[cc] : ctx_lds[s * 64 + (cc - 64)];
        a = fmaf(mp[cc * 80], xv, a);
      }
      atomicAdd(&out[(size_t)b * 80000 + it * 80 + tid], a);
    }
    // ---- G1: decP partial (a = t8, hh chunk of 16) ----
    {
      float gd = 0.f;
#pragma unroll
      for (int i = 0; i < 4; ++i) {
        float4 w = wd4[(size_t)i << 8];
        int hb = chunk * 16 + i * 4;
        gd = fmaf(w.x, h_lds[hb + 0], gd); gd = fmaf(w.y, h_lds[hb + 1], gd);
        gd = fmaf(w.z, h_lds[hb + 2], gd); gd = fmaf(w.w, h_lds[hb + 3], gd);
      }
      dpart_lds[tid] = gd;
    }
    // ---- G2: ghP full row (rr = tid) ----
    {
      float gh = 0.f;
#pragma unroll
      for (int hq = 0; hq < 16; ++hq) {
        float4 w = wh4[(size_t)hq << 10];
        gh = fmaf(w.x, h_lds[hq * 4 + 0], gh); gh = fmaf(w.y, h_lds[hq * 4 + 1], gh);
        gh = fmaf(w.z, h_lds[hq * 4 + 2], gh); gh = fmaf(w.w, h_lds[hq * 4 + 3], gh);
      }
      agstore(ghP + ((size_t)(pn * 64 + b) * 4 + s) * 1024 + tid, gh);
    }
    __syncthreads();
    if (tid < 256)
      agstore(decP + ((size_t)(pn * 64 + b) * 4 + s) * 256 + t8,
              dpart_lds[t8] + dpart_lds[256 + t8] + dpart_lds[512 + t8] + dpart_lds[768 + t8]);
    if (tid == 0) {
      float st = (s == 0) ? stop_b[0] : 0.f;
      for (int i2 = 0; i2 < 128; ++i2) st += stop_lds[i2];
      atomicAdd(&out[(size_t)5120000 + b * 1000 + it], st);
    }
    // ================= barrier 2 =================
    __threadfence();
    __syncthreads();
    if (tid == 0) {
      ++epoch;
      __hip_atomic_fetch_add(ctrb, 1u, __ATOMIC_RELEASE, __HIP_MEMORY_SCOPE_AGENT);
      while (__hip_atomic_load(ctrb, __ATOMIC_ACQUIRE, __HIP_MEMORY_SCOPE_AGENT) < 4u * epoch)
        __builtin_amdgcn_s_sleep(1);
    }
    __syncthreads();
  }
}

extern "C" void kernel_launch(void* const* d_in, const int* in_sizes, int n_in,
                              void* d_out, int out_size, void* d_ws, size_t ws_size,
                              hipStream_t stream) {
  const float* enc = (const float*)d_in[0];
  const float* tmel = (const float*)d_in[1];
  const float* W_enc = (const float*)d_in[2];
  const float* b_enc = (const float*)d_in[3];
  const float* W_dec = (const float*)d_in[4];
  const float* b_dec = (const float*)d_in[5];
  const float* v_w = (const float*)d_in[6];
  const float* v_b = (const float*)d_in[7];
  const float* pW1 = (const float*)d_in[8];
  const float* pb1 = (const float*)d_in[9];
  const float* pW2 = (const float*)d_in[10];
  const float* pb2 = (const float*)d_in[11];
  const float* W_ih = (const float*)d_in[12];
  const float* W_hh = (const float*)d_in[13];
  const float* b_ih = (const float*)d_in[14];
  const float* b_hh = (const float*)d_in[15];
  const float* mel_W = (const float*)d_in[16];
  const float* mel_b = (const float*)d_in[17];
  const float* stop_W = (const float*)d_in[18];
  const float* stop_b = (const float*)d_in[19];
  const float* emask = (const float*)d_in[20];

  if (ws_size < WS_NEED) return;  // fail-visible rather than corrupt

  char* ws = (char*)d_ws;
  unsigned short* attn8 = (unsigned short*)(ws + OFF_ATTN8);
  unsigned short* pre2 = (unsigned short*)(ws + OFF_PRE2);
  float* Wg4 = (float*)(ws + OFF_WG4);
  float* Wp4 = (float*)(ws + OFF_WP4);
  float* Whh4 = (float*)(ws + OFF_WHH4);
  float* Wdec4 = (float*)(ws + OFF_WDEC4);
  float* MelT = (float*)(ws + OFF_MELT);
  float* StopT = (float*)(ws + OFF_STOPT);
  float* biasG = (float*)(ws + OFF_BIASG);
  float* exch = (float*)(ws + OFF_EXCH);
  unsigned* ctr = (unsigned*)(exch + EXF_CTR);

  hipMemsetAsync(exch, 0, SZ_EXCH, stream);
  hipMemsetAsync(d_out, 0, (size_t)out_size * 4, stream);

  prep_weights<<<2470, 256, 0, stream>>>(W_ih, W_hh, W_dec, mel_W, stop_W, b_ih, b_hh,
                                         Wg4, Wp4, Whh4, Wdec4, MelT, StopT, biasG);
  attn_gemm<<<1024, 256, 0, stream>>>(enc, W_enc, b_enc, attn8);
  prenet_fused<<<1000, 256, 0, stream>>>(tmel, pW1, pb1, pW2, pb2, pre2);
  decoder_loop<<<256, 1024, 0, stream>>>(attn8, enc, pre2, Wg4, Wp4, Whh4, Wdec4,
                                         MelT, StopT, biasG, exch, ctr, b_dec, v_w, v_b,
                                         emask, mel_b, stop_b, (float*)d_out);
}

// Round 5
// 168483.350 us; speedup vs baseline: 1.6330x; 1.6330x over previous
//
#include <hip/hip_runtime.h>
#include <hip/hip_bf16.h>

#define NMEL 80

__device__ __forceinline__ float bf2f(unsigned short u) {
  unsigned v = ((unsigned)u) << 16; float f; __builtin_memcpy(&f, &v, 4); return f;
}
__device__ __forceinline__ unsigned short f2bf_u(float f) {
  __hip_bfloat16 h = __float2bfloat16(f); unsigned short u; __builtin_memcpy(&u, &h, 2); return u;
}
__device__ __forceinline__ float agload(const float* p) {
  return __hip_atomic_load(p, __ATOMIC_RELAXED, __HIP_MEMORY_SCOPE_AGENT);
}
__device__ __forceinline__ void agstore(float* p, float v) {
  __hip_atomic_store(p, v, __ATOMIC_RELAXED, __HIP_MEMORY_SCOPE_AGENT);
}
__device__ __forceinline__ void unpk(unsigned u, float& lo, float& hi) {
  unsigned l = u << 16, h = u & 0xffff0000u;
  __builtin_memcpy(&lo, &l, 4); __builtin_memcpy(&hi, &h, 4);
}

// ---------------- workspace layout (bytes) ----------------
// attnR: bf16, reg-resident layout: uint4 idx = (((b*4+s)*4+chunk)*8+j)*256 + te_loc
//        packs a = chunk*64 + j*8 + 0..7 (pre-scaled by 2*log2e)
constexpr size_t OFF_ATTNR = 0;
constexpr size_t SZ_ATTNR = (size_t)64 * 256 * 1024 * 2;           // 33,554,432
constexpr size_t OFF_ENCBF = OFF_ATTNR + SZ_ATTNR;                 // bf16 [b][te][d]
constexpr size_t SZ_ENCBF = (size_t)64 * 1024 * 256 * 2;
constexpr size_t OFF_PRE2 = OFF_ENCBF + SZ_ENCBF;                  // bf16 [64000][256]
constexpr size_t SZ_PRE2 = (size_t)64000 * 256 * 2;
constexpr size_t OFF_WG4 = OFF_PRE2 + SZ_PRE2;                     // f32 [4][64][256][4]
constexpr size_t SZ_W4 = (size_t)262144 * 4;
constexpr size_t OFF_WP4 = OFF_WG4 + SZ_W4;
constexpr size_t OFF_WHH4 = OFF_WP4 + SZ_W4;                       // f32 [4][16][1024][4]
constexpr size_t OFF_WDEC4 = OFF_WHH4 + SZ_W4;                     // f32 [4][16][256][4]
constexpr size_t SZ_WDEC4 = (size_t)65536 * 4;
constexpr size_t OFF_MELT = OFF_WDEC4 + SZ_WDEC4;                  // f32 [4][128][80]
constexpr size_t SZ_MELT = (size_t)4 * 128 * 80 * 4;
constexpr size_t OFF_STOPT = OFF_MELT + SZ_MELT;                   // f32 [4][128]
constexpr size_t SZ_STOPT = (size_t)4 * 128 * 4;
constexpr size_t OFF_BIASG = OFF_STOPT + SZ_STOPT;                 // f32 [4][256]
constexpr size_t SZ_BIASG = (size_t)4 * 256 * 4;
constexpr size_t OFF_EXCH = (OFF_BIASG + SZ_BIASG + 255) & ~(size_t)255;
constexpr size_t EXF_DEC = 0;                          // [2][64][4][256]
constexpr size_t EXN_DEC = (size_t)2 * 64 * 4 * 256;
constexpr size_t EXF_GH = EXF_DEC + EXN_DEC;           // [2][64][4][1024]
constexpr size_t EXN_GH = (size_t)2 * 64 * 4 * 1024;
constexpr size_t EXF_CTX = EXF_GH + EXN_GH;            // [64][4][256]
constexpr size_t EXN_CTX = (size_t)64 * 4 * 256;
constexpr size_t EXF_S = EXF_CTX + EXN_CTX;            // [64][16]
constexpr size_t EXN_S = 64 * 16;
constexpr size_t EXF_CTR = EXF_S + EXN_S;              // u32 [64][16]
constexpr size_t EXN_CTR = 64 * 16;
constexpr size_t EXCH_FLOATS = EXF_CTR + EXN_CTR;
constexpr size_t SZ_EXCH = EXCH_FLOATS * 4;
constexpr size_t WS_NEED = OFF_EXCH + SZ_EXCH;         // ~101.4 MiB (== round-2 proven size)

// ---------------- fp32 -> bf16 convert (enc) ----------------
__global__ __launch_bounds__(256) void conv_bf16(const float* __restrict__ in,
                                                 unsigned short* __restrict__ out, int n) {
  int i = (blockIdx.x * 256 + threadIdx.x) * 2;
  if (i < n) {
    float2 v = *(const float2*)(in + i);
    unsigned pair = (unsigned)f2bf_u(v.x) | ((unsigned)f2bf_u(v.y) << 16);
    *(unsigned*)(out + i) = pair;
  }
}

// ---------------- weight re-layout (fp32 packed-4) ----------------
__global__ __launch_bounds__(256) void prep_weights(
    const float* __restrict__ W_ih, const float* __restrict__ W_hh,
    const float* __restrict__ W_dec, const float* __restrict__ mel_W,
    const float* __restrict__ stop_W, const float* __restrict__ b_ih,
    const float* __restrict__ b_hh,
    float* __restrict__ Wg4, float* __restrict__ Wp4,
    float* __restrict__ Whh4, float* __restrict__ Wdec4,
    float* __restrict__ MelT, float* __restrict__ StopT, float* __restrict__ biasG) {
  int idx = blockIdx.x * 256 + threadIdx.x;
  if (idx < 262144) {
    int q = idx & 3, r = (idx >> 2) & 255, kq = (idx >> 10) & 63, s = idx >> 16;
    int grow = ((r >> 6) << 8) + s * 64 + (r & 63);
    Wg4[idx] = W_ih[(size_t)grow * 512 + 256 + kq * 4 + q];
    Wp4[idx] = W_ih[(size_t)grow * 512 + kq * 4 + q];
  } else if (idx < 524288) {
    int i = idx - 262144;
    int q = i & 3, rr = (i >> 2) & 1023, hq = (i >> 12) & 15, s = i >> 16;
    Whh4[i] = W_hh[(size_t)rr * 256 + s * 64 + hq * 4 + q];
  } else if (idx < 589824) {
    int i = idx - 524288;
    int q = i & 3, a = (i >> 2) & 255, hq = (i >> 10) & 15, s = (i >> 14) & 3;
    Wdec4[i] = W_dec[(size_t)a * 256 + s * 64 + hq * 4 + q];
  } else if (idx < 589824 + 40960) {
    int k = idx - 589824;
    int m = k % 80, r = k / 80;
    int cc = r & 127, s = r >> 7;
    int col = (cc < 64) ? (s * 64 + cc) : (256 + s * 64 + (cc - 64));
    MelT[k] = mel_W[(size_t)m * 512 + col];
  } else if (idx < 589824 + 40960 + 512) {
    int k = idx - (589824 + 40960);
    int cc = k & 127, s = k >> 7;
    int col = (cc < 64) ? (s * 64 + cc) : (256 + s * 64 + (cc - 64));
    StopT[k] = stop_W[col];
  } else if (idx < 589824 + 40960 + 512 + 1024) {
    int k = idx - (589824 + 40960 + 512);
    int j = k & 255, s = k >> 8;
    int row = ((j >> 6) << 8) + s * 64 + (j & 63);
    biasG[k] = b_ih[row] + b_hh[row];
  }
}

// ---------------- attn_enc GEMM -> reg-resident bf16 layout attnR ----------------
__global__ __launch_bounds__(256) void attn_gemm(const float* __restrict__ enc,
                                                 const float* __restrict__ W_enc,
                                                 const float* __restrict__ b_enc,
                                                 unsigned* __restrict__ attnR) {
  __shared__ unsigned short Alds[64 * 260];
  const int tid = threadIdx.x;
  const int row0 = blockIdx.x * 64;
  const int wv = tid >> 6, lane = tid & 63, nb = wv * 64;
  for (int idx = tid; idx < 64 * 256; idx += 256) {
    int r = idx >> 8, k = idx & 255;
    Alds[r * 260 + k] = f2bf_u(enc[(size_t)(row0 + r) * 256 + k]);
  }
  __syncthreads();
  float acc[64];
#pragma unroll
  for (int n = 0; n < 64; ++n) acc[n] = b_enc[nb + n];
  for (int k8 = 0; k8 < 256; k8 += 8) {
    ushort4 ua = *(const ushort4*)&Alds[lane * 260 + k8];
    ushort4 ub = *(const ushort4*)&Alds[lane * 260 + k8 + 4];
    float a0 = bf2f(ua.x), a1 = bf2f(ua.y), a2 = bf2f(ua.z), a3 = bf2f(ua.w);
    float a4 = bf2f(ub.x), a5 = bf2f(ub.y), a6 = bf2f(ub.z), a7 = bf2f(ub.w);
#pragma unroll
    for (int n = 0; n < 64; ++n) {
      const float4* wp = (const float4*)(W_enc + (size_t)(nb + n) * 256 + k8);
      float4 w0 = wp[0], w1 = wp[1];
      acc[n] = fmaf(a0, w0.x, acc[n]); acc[n] = fmaf(a1, w0.y, acc[n]);
      acc[n] = fmaf(a2, w0.z, acc[n]); acc[n] = fmaf(a3, w0.w, acc[n]);
      acc[n] = fmaf(a4, w1.x, acc[n]); acc[n] = fmaf(a5, w1.y, acc[n]);
      acc[n] = fmaf(a6, w1.z, acc[n]); acc[n] = fmaf(a7, w1.w, acc[n]);
    }
  }
  const float CE = 2.8853900817779268f;  // 2*log2(e)
  const int b = row0 >> 10;
  const int te_g = (row0 & 1023) + lane;
  const int sl = te_g >> 8, te_loc = te_g & 255;
#pragma unroll
  for (int n = 0; n < 64; n += 2) {
    int a = nb + n;
    unsigned pair = (unsigned)f2bf_u(acc[n] * CE) | ((unsigned)f2bf_u(acc[n + 1] * CE) << 16);
    size_t u4 = ((((size_t)(b * 4 + sl) * 4 + (a >> 6)) * 8 + ((a >> 3) & 7)) * 256 + te_loc);
    attnR[u4 * 4 + ((a & 7) >> 1)] = pair;
  }
}

// ---------------- fused prenet ----------------
__global__ __launch_bounds__(256) void prenet_fused(const float* __restrict__ tmel,
                                                    const float* __restrict__ W1,
                                                    const float* __restrict__ b1,
                                                    const float* __restrict__ W2,
                                                    const float* __restrict__ b2,
                                                    unsigned short* __restrict__ pre2) {
  __shared__ unsigned short Alds[64 * 260];
  const int tid = threadIdx.x;
  const int row0 = blockIdx.x * 64;
  const int wv = tid >> 6, lane = tid & 63, nb = wv * 64;
  for (int idx = tid; idx < 64 * 80; idx += 256) {
    int r = idx / 80, k = idx - r * 80;
    int R = row0 + r;
    float v = (R % 1000 != 0) ? tmel[(size_t)(R - 1) * NMEL + k] : 0.f;
    Alds[r * 260 + k] = f2bf_u(v);
  }
  __syncthreads();
  float acc[64];
#pragma unroll
  for (int n = 0; n < 64; ++n) acc[n] = b1[nb + n];
  for (int k8 = 0; k8 < 80; k8 += 8) {
    ushort4 ua = *(const ushort4*)&Alds[lane * 260 + k8];
    ushort4 ub = *(const ushort4*)&Alds[lane * 260 + k8 + 4];
    float a0 = bf2f(ua.x), a1 = bf2f(ua.y), a2 = bf2f(ua.z), a3 = bf2f(ua.w);
    float a4 = bf2f(ub.x), a5 = bf2f(ub.y), a6 = bf2f(ub.z), a7 = bf2f(ub.w);
#pragma unroll
    for (int n = 0; n < 64; ++n) {
      const float4* wp = (const float4*)(W1 + (size_t)(nb + n) * 80 + k8);
      float4 w0 = wp[0], w1 = wp[1];
      acc[n] = fmaf(a0, w0.x, acc[n]); acc[n] = fmaf(a1, w0.y, acc[n]);
      acc[n] = fmaf(a2, w0.z, acc[n]); acc[n] = fmaf(a3, w0.w, acc[n]);
      acc[n] = fmaf(a4, w1.x, acc[n]); acc[n] = fmaf(a5, w1.y, acc[n]);
      acc[n] = fmaf(a6, w1.z, acc[n]); acc[n] = fmaf(a7, w1.w, acc[n]);
    }
  }
  __syncthreads();
#pragma unroll
  for (int n = 0; n < 64; ++n) Alds[lane * 260 + nb + n] = f2bf_u(fmaxf(acc[n], 0.f));
  __syncthreads();
#pragma unroll
  for (int n = 0; n < 64; ++n) acc[n] = b2[nb + n];
  for (int k8 = 0; k8 < 256; k8 += 8) {
    ushort4 ua = *(const ushort4*)&Alds[lane * 260 + k8];
    ushort4 ub = *(const ushort4*)&Alds[lane * 260 + k8 + 4];
    float a0 = bf2f(ua.x), a1 = bf2f(ua.y), a2 = bf2f(ua.z), a3 = bf2f(ua.w);
    float a4 = bf2f(ub.x), a5 = bf2f(ub.y), a6 = bf2f(ub.z), a7 = bf2f(ub.w);
#pragma unroll
    for (int n = 0; n < 64; ++n) {
      const float4* wp = (const float4*)(W2 + (size_t)(nb + n) * 256 + k8);
      float4 w0 = wp[0], w1 = wp[1];
      acc[n] = fmaf(a0, w0.x, acc[n]); acc[n] = fmaf(a1, w0.y, acc[n]);
      acc[n] = fmaf(a2, w0.z, acc[n]); acc[n] = fmaf(a3, w0.w, acc[n]);
      acc[n] = fmaf(a4, w1.x, acc[n]); acc[n] = fmaf(a5, w1.y, acc[n]);
      acc[n] = fmaf(a6, w1.z, acc[n]); acc[n] = fmaf(a7, w1.w, acc[n]);
    }
  }
  __syncthreads();
#pragma unroll
  for (int n = 0; n < 64; ++n) Alds[lane * 260 + nb + n] = f2bf_u(fmaxf(acc[n], 0.f));
  __syncthreads();
  for (int idx = tid; idx < 64 * 128; idx += 256) {
    int r = idx >> 7, k2 = (idx & 127) * 2;
    unsigned pair = (unsigned)Alds[r * 260 + k2] | ((unsigned)Alds[r * 260 + k2 + 1] << 16);
    *(unsigned*)(pre2 + (size_t)(row0 + r) * 256 + k2) = pair;
  }
}

// ---------------- persistent decoder: attn_enc + enc resident in VGPRs ----------------
// 256 WGs x 1024 threads; b = wg&63, s = wg>>6 (4 slices of b share XCD b%8).
__global__ __launch_bounds__(1024) void decoder_loop(
    const unsigned* __restrict__ attnR, const unsigned short* __restrict__ encbf,
    const unsigned short* __restrict__ pre2,
    const float* __restrict__ Wg4, const float* __restrict__ Wp4,
    const float* __restrict__ Whh4, const float* __restrict__ Wdec4,
    const float* __restrict__ MelT, const float* __restrict__ StopT,
    const float* __restrict__ biasG,
    float* exch, unsigned* ctr,
    const float* __restrict__ b_dec, const float* __restrict__ v_w,
    const float* __restrict__ v_b, const float* __restrict__ enc_mask,
    const float* __restrict__ mel_b, const float* __restrict__ stop_b,
    float* out) {
  __shared__ __align__(16) float scratch[4096];   // partials / gathers (reused per phase)
  __shared__ __align__(16) float melT_lds[10240];
  __shared__ float stopT_lds[128];
  __shared__ __align__(16) float dec_lds[256];
  __shared__ __align__(16) float v2_lds[256];
  __shared__ __align__(16) float p_lds[256];
  __shared__ __align__(16) float ctx_lds[256];
  __shared__ __align__(16) float pre_lds[256];
  __shared__ float gates_lds[256];
  __shared__ float c_lds[64], h_lds[64];
  __shared__ float red_lds[16];
  __shared__ float sv_lds;

  const int tid = threadIdx.x;
  const int b = blockIdx.x & 63, s = blockIdx.x >> 6;
  const int t8 = tid & 255;
  const int chunk = tid >> 8;
  const int lane = tid & 63, wid = tid >> 6;
  const int w = tid >> 6;      // wave id 0..15 (context te-group)
  const float CE = 2.8853900817779268f;   // 2*log2(e)
  const float L2E = 1.4426950408889634f;  // log2(e)

  // ---- one-time init: LDS tables ----
  if (tid < 256) {
    v2_lds[tid] = -2.f * v_w[tid];
    if (tid < 64) c_lds[tid] = 0.f;
    float sp = v_w[tid];
    for (int m = 32; m; m >>= 1) sp += __shfl_xor(sp, m);
    if (lane == 0) red_lds[wid] = sp;
  }
  for (int i = tid; i < 10240; i += 1024) melT_lds[i] = MelT[(size_t)s * 10240 + i];
  if (tid >= 512 && tid < 640) stopT_lds[tid - 512] = StopT[s * 128 + (tid - 512)];
  __syncthreads();
  if (tid == 0) sv_lds = red_lds[0] + red_lds[1] + red_lds[2] + red_lds[3];
  __syncthreads();
  const float Sv = sv_lds;
  const float vb = v_b[0];
  const float maskv = (tid < 256) ? enc_mask[b * 1024 + s * 256 + tid] : 0.f;
  const float bdec_r = (tid < 256) ? b_dec[tid] : 0.f;
  const float biasg_r = (tid < 256) ? biasG[s * 256 + tid] : 0.f;

  // ---- one-time init: VGPR-resident attn_enc + enc slices ----
  // attn_r4[j] packs a = chunk*64 + j*8 + 0..7 for te = t8 (bf16, pre-scaled CE)
  uint4 attn_r4[8];
  {
    const uint4* apR = (const uint4*)attnR + (((size_t)(b * 4 + s) * 4 + chunk) * 8) * 256 + t8;
#pragma unroll
    for (int j = 0; j < 8; ++j) attn_r4[j] = apR[(size_t)j << 8];
  }
  // enc_r2[t] packs d = 4*lane..4*lane+3 for te = w*16 + t (bf16)
  uint2 enc_r2[16];
  {
    const uint2* epR = (const uint2*)encbf + ((size_t)(b * 1024 + s * 256 + w * 16)) * 64 + lane;
#pragma unroll
    for (int t = 0; t < 16; ++t) enc_r2[t] = epR[(size_t)t << 6];
  }

  const int grow = ((t8 >> 6) << 8) + s * 64 + (t8 & 63);
  const float4* wg4 = (const float4*)Wg4 + ((size_t)(s * 64 + chunk * 16)) * 256 + t8;
  const float4* wp4 = (const float4*)Wp4 + ((size_t)(s * 64 + chunk * 16)) * 256 + t8;
  const float4* wh4 = (const float4*)Whh4 + ((size_t)s) * 16384 + tid;
  const float4* wd4 = (const float4*)Wdec4 + ((size_t)(s * 16 + chunk * 4)) * 256 + t8;
  const unsigned short* pre2_b = pre2 + (size_t)b * 256000;

  float* decP = exch + EXF_DEC;
  float* ghP = exch + EXF_GH;
  float* ctxP = exch + EXF_CTX;
  float* sP = exch + EXF_S;
  unsigned* ctrb = ctr + b * 16;
  unsigned epoch = 0;

  for (int it = 0; it < 1000; ++it) {
    const int par = it & 1;
    const int pn = par ^ 1;
    float prefv = (tid < 256) ? bf2f(pre2_b[it * 256 + tid]) : 0.f;
    // ---- A0: gather decP partials ----
    scratch[tid] = agload(decP + ((size_t)(par * 64 + b)) * 1024 + tid);
    __syncthreads();
    if (tid < 256)
      dec_lds[tid] = (bdec_r + scratch[tid] + scratch[256 + tid] + scratch[512 + tid] +
                      scratch[768 + tid]) * CE;
    __syncthreads();
    // ---- A1: energy partial (attn from VGPRs, dec/v2 broadcast from LDS) ----
    {
      float acc = 0.f;
#pragma unroll
      for (int j = 0; j < 8; ++j) {
        uint4 u = attn_r4[j];
        int ab = chunk * 64 + j * 8;
        float4 d0 = *(const float4*)&dec_lds[ab];
        float4 d1 = *(const float4*)&dec_lds[ab + 4];
        float4 v0 = *(const float4*)&v2_lds[ab];
        float4 v1 = *(const float4*)&v2_lds[ab + 4];
        float t0, t1, t2, t3, t4, t5, t6, t7;
        unpk(u.x, t0, t1); unpk(u.y, t2, t3); unpk(u.z, t4, t5); unpk(u.w, t6, t7);
        acc = fmaf(v0.x, __builtin_amdgcn_rcpf(1.f + __builtin_amdgcn_exp2f(t0 + d0.x)), acc);
        acc = fmaf(v0.y, __builtin_amdgcn_rcpf(1.f + __builtin_amdgcn_exp2f(t1 + d0.y)), acc);
        acc = fmaf(v0.z, __builtin_amdgcn_rcpf(1.f + __builtin_amdgcn_exp2f(t2 + d0.z)), acc);
        acc = fmaf(v0.w, __builtin_amdgcn_rcpf(1.f + __builtin_amdgcn_exp2f(t3 + d0.w)), acc);
        acc = fmaf(v1.x, __builtin_amdgcn_rcpf(1.f + __builtin_amdgcn_exp2f(t4 + d1.x)), acc);
        acc = fmaf(v1.y, __builtin_amdgcn_rcpf(1.f + __builtin_amdgcn_exp2f(t5 + d1.y)), acc);
        acc = fmaf(v1.z, __builtin_amdgcn_rcpf(1.f + __builtin_amdgcn_exp2f(t6 + d1.z)), acc);
        acc = fmaf(v1.w, __builtin_amdgcn_rcpf(1.f + __builtin_amdgcn_exp2f(t7 + d1.w)), acc);
      }
      scratch[tid] = acc;
    }
    __syncthreads();
    // ---- A2: softmax numerator + slice sum ----
    if (tid < 256) {
      float e = Sv + vb + scratch[t8] + scratch[256 + t8] + scratch[512 + t8] + scratch[768 + t8];
      float p = (maskv != 0.f) ? __builtin_amdgcn_exp2f(e * L2E) : 0.f;
      p_lds[t8] = p;
      float sp = p;
      for (int m = 32; m; m >>= 1) sp += __shfl_xor(sp, m);
      if (lane == 0) red_lds[wid] = sp;
    }
    __syncthreads();
    // ---- B: context partials (enc from VGPRs; wave w owns te w*16..w*16+15) ----
    {
      float c0 = 0, c1 = 0, c2 = 0, c3 = 0;
#pragma unroll
      for (int t = 0; t < 16; ++t) {
        float pv = p_lds[w * 16 + t];
        float e0, e1, e2, e3;
        unpk(enc_r2[t].x, e0, e1);
        unpk(enc_r2[t].y, e2, e3);
        c0 = fmaf(pv, e0, c0); c1 = fmaf(pv, e1, c1);
        c2 = fmaf(pv, e2, c2); c3 = fmaf(pv, e3, c3);
      }
      float* cb = &scratch[w * 256 + lane * 4];
      cb[0] = c0; cb[1] = c1; cb[2] = c2; cb[3] = c3;
      if (tid < 256) pre_lds[tid] = prefv;
    }
    __syncthreads();
    // ---- B2: reduce 16 waves -> publish slice context + softmax sum ----
    if (tid < 256) {
      float cp = 0.f;
#pragma unroll
      for (int ww = 0; ww < 16; ++ww) cp += scratch[ww * 256 + t8];
      agstore(ctxP + ((size_t)b * 4 + s) * 256 + t8, cp);
    }
    if (tid == 0)
      agstore(sP + b * 16 + s, red_lds[0] + red_lds[1] + red_lds[2] + red_lds[3]);
    // ================= barrier 1 =================
    __threadfence();
    __syncthreads();
    if (tid == 0) {
      ++epoch;
      __hip_atomic_fetch_add(ctrb, 1u, __ATOMIC_RELEASE, __HIP_MEMORY_SCOPE_AGENT);
      while (__hip_atomic_load(ctrb, __ATOMIC_ACQUIRE, __HIP_MEMORY_SCOPE_AGENT) < 4u * epoch)
        __builtin_amdgcn_s_sleep(1);
    }
    __syncthreads();
    // ---- C: final normalized context ----
    scratch[tid] = agload(ctxP + ((size_t)b * 4 + chunk) * 256 + t8);
    if (tid < 4) red_lds[8 + tid] = agload(sP + b * 16 + tid);
    __syncthreads();
    if (tid < 256) {
      float rS = 1.f / (red_lds[8] + red_lds[9] + red_lds[10] + red_lds[11]);
      ctx_lds[t8] = (scratch[t8] + scratch[256 + t8] + scratch[512 + t8] + scratch[768 + t8]) * rS;
    }
    __syncthreads();
    // ---- D: gate partials (fp32 weights from L2) ----
    {
      float g = agload(ghP + ((size_t)(par * 64 + b)) * 4096 + chunk * 1024 + grow);
#pragma unroll 8
      for (int i = 0; i < 16; ++i) {
        float4 wv = wg4[(size_t)i << 8];
        float4 qv = wp4[(size_t)i << 8];
        int kb = chunk * 64 + i * 4;
        float4 x = *(const float4*)&ctx_lds[kb];
        float4 y = *(const float4*)&pre_lds[kb];
        g = fmaf(wv.x, x.x, g); g = fmaf(wv.y, x.y, g);
        g = fmaf(wv.z, x.z, g); g = fmaf(wv.w, x.w, g);
        g = fmaf(qv.x, y.x, g); g = fmaf(qv.y, y.y, g);
        g = fmaf(qv.z, y.z, g); g = fmaf(qv.w, y.w, g);
      }
      scratch[tid] = g;
    }
    __syncthreads();
    if (tid < 256)
      gates_lds[t8] = biasg_r + scratch[t8] + scratch[256 + t8] + scratch[512 + t8] +
                      scratch[768 + t8];
    __syncthreads();
    // ---- E: LSTM pointwise ----
    if (tid < 64) {
      float ii = gates_lds[tid], ff = gates_lds[64 + tid];
      float gg = gates_lds[128 + tid], oo = gates_lds[192 + tid];
      float c = c_lds[tid];
      float si = __builtin_amdgcn_rcpf(1.f + __builtin_amdgcn_exp2f(-ii * L2E));
      float sf = __builtin_amdgcn_rcpf(1.f + __builtin_amdgcn_exp2f(-ff * L2E));
      float so = __builtin_amdgcn_rcpf(1.f + __builtin_amdgcn_exp2f(-oo * L2E));
      float tg2 = 1.f - 2.f * __builtin_amdgcn_rcpf(1.f + __builtin_amdgcn_exp2f(gg * CE));
      float cn = sf * c + si * tg2;
      float tc = 1.f - 2.f * __builtin_amdgcn_rcpf(1.f + __builtin_amdgcn_exp2f(cn * CE));
      c_lds[tid] = cn;
      h_lds[tid] = so * tc;
    }
    __syncthreads();
    // ---- F: mel head (LDS table) + stop partial (waves 8,9) ----
    if (tid < 80) {
      float a = (s == 0) ? mel_b[tid] : 0.f;
#pragma unroll 8
      for (int cc = 0; cc < 128; ++cc) {
        float xv = (cc < 64) ? h_lds[cc] : ctx_lds[s * 64 + (cc - 64)];
        a = fmaf(melT_lds[cc * 80 + tid], xv, a);
      }
      atomicAdd(&out[(size_t)b * 80000 + it * 80 + tid], a);
    }
    if (tid >= 512 && tid < 640) {
      int cc = tid - 512;
      float xv = (cc < 64) ? h_lds[cc] : ctx_lds[s * 64 + (cc - 64)];
      float sv2 = stopT_lds[cc] * xv;
      for (int m = 32; m; m >>= 1) sv2 += __shfl_xor(sv2, m);
      if (lane == 0) red_lds[12 + ((tid - 512) >> 6)] = sv2;
    }
    // ---- G1: decP partial ----
    {
      float gd = 0.f;
#pragma unroll
      for (int i = 0; i < 4; ++i) {
        float4 wv = wd4[(size_t)i << 8];
        int hb = chunk * 16 + i * 4;
        gd = fmaf(wv.x, h_lds[hb + 0], gd); gd = fmaf(wv.y, h_lds[hb + 1], gd);
        gd = fmaf(wv.z, h_lds[hb + 2], gd); gd = fmaf(wv.w, h_lds[hb + 3], gd);
      }
      // ---- G2: ghP full row (rr = tid) ----
      float gh = 0.f;
#pragma unroll 8
      for (int hq = 0; hq < 16; ++hq) {
        float4 wv = wh4[(size_t)hq << 10];
        gh = fmaf(wv.x, h_lds[hq * 4 + 0], gh); gh = fmaf(wv.y, h_lds[hq * 4 + 1], gh);
        gh = fmaf(wv.z, h_lds[hq * 4 + 2], gh); gh = fmaf(wv.w, h_lds[hq * 4 + 3], gh);
      }
      agstore(ghP + ((size_t)(pn * 64 + b) * 4 + s) * 1024 + tid, gh);
      scratch[tid] = gd;
    }
    __syncthreads();
    if (tid < 256)
      agstore(decP + ((size_t)(pn * 64 + b) * 4 + s) * 256 + t8,
              scratch[t8] + scratch[256 + t8] + scratch[512 + t8] + scratch[768 + t8]);
    if (tid == 0) {
      float st = (s == 0) ? stop_b[0] : 0.f;
      atomicAdd(&out[(size_t)5120000 + b * 1000 + it], st + red_lds[12] + red_lds[13]);
    }
    // ================= barrier 2 =================
    __threadfence();
    __syncthreads();
    if (tid == 0) {
      ++epoch;
      __hip_atomic_fetch_add(ctrb, 1u, __ATOMIC_RELEASE, __HIP_MEMORY_SCOPE_AGENT);
      while (__hip_atomic_load(ctrb, __ATOMIC_ACQUIRE, __HIP_MEMORY_SCOPE_AGENT) < 4u * epoch)
        __builtin_amdgcn_s_sleep(1);
    }
    __syncthreads();
  }
}

extern "C" void kernel_launch(void* const* d_in, const int* in_sizes, int n_in,
                              void* d_out, int out_size, void* d_ws, size_t ws_size,
                              hipStream_t stream) {
  const float* enc = (const float*)d_in[0];
  const float* tmel = (const float*)d_in[1];
  const float* W_enc = (const float*)d_in[2];
  const float* b_enc = (const float*)d_in[3];
  const float* W_dec = (const float*)d_in[4];
  const float* b_dec = (const float*)d_in[5];
  const float* v_w = (const float*)d_in[6];
  const float* v_b = (const float*)d_in[7];
  const float* pW1 = (const float*)d_in[8];
  const float* pb1 = (const float*)d_in[9];
  const float* pW2 = (const float*)d_in[10];
  const float* pb2 = (const float*)d_in[11];
  const float* W_ih = (const float*)d_in[12];
  const float* W_hh = (const float*)d_in[13];
  const float* b_ih = (const float*)d_in[14];
  const float* b_hh = (const float*)d_in[15];
  const float* mel_W = (const float*)d_in[16];
  const float* mel_b = (const float*)d_in[17];
  const float* stop_W = (const float*)d_in[18];
  const float* stop_b = (const float*)d_in[19];
  const float* emask = (const float*)d_in[20];

  if (ws_size < WS_NEED) return;  // fail-visible rather than corrupt

  char* ws = (char*)d_ws;
  unsigned* attnR = (unsigned*)(ws + OFF_ATTNR);
  unsigned short* encbf = (unsigned short*)(ws + OFF_ENCBF);
  unsigned short* pre2 = (unsigned short*)(ws + OFF_PRE2);
  float* Wg4 = (float*)(ws + OFF_WG4);
  float* Wp4 = (float*)(ws + OFF_WP4);
  float* Whh4 = (float*)(ws + OFF_WHH4);
  float* Wdec4 = (float*)(ws + OFF_WDEC4);
  float* MelT = (float*)(ws + OFF_MELT);
  float* StopT = (float*)(ws + OFF_STOPT);
  float* biasG = (float*)(ws + OFF_BIASG);
  float* exch = (float*)(ws + OFF_EXCH);
  unsigned* ctr = (unsigned*)(exch + EXF_CTR);

  hipMemsetAsync(exch, 0, SZ_EXCH, stream);
  hipMemsetAsync(d_out, 0, (size_t)out_size * 4, stream);

  conv_bf16<<<32768, 256, 0, stream>>>(enc, encbf, 64 * 1024 * 256);
  prep_weights<<<2470, 256, 0, stream>>>(W_ih, W_hh, W_dec, mel_W, stop_W, b_ih, b_hh,
                                         Wg4, Wp4, Whh4, Wdec4, MelT, StopT, biasG);
  attn_gemm<<<1024, 256, 0, stream>>>(enc, W_enc, b_enc, attnR);
  prenet_fused<<<1000, 256, 0, stream>>>(tmel, pW1, pb1, pW2, pb2, pre2);
  decoder_loop<<<256, 1024, 0, stream>>>(attnR, encbf, pre2, Wg4, Wp4, Whh4, Wdec4,
                                         MelT, StopT, biasG, exch, ctr, b_dec, v_w, v_b,
                                         emask, mel_b, stop_b, (float*)d_out);
}

// Round 6
// 165651.648 us; speedup vs baseline: 1.6609x; 1.0171x over previous
//
#include <hip/hip_runtime.h>
#include <hip/hip_bf16.h>

#define NMEL 80

__device__ __forceinline__ float bf2f(unsigned short u) {
  unsigned v = ((unsigned)u) << 16; float f; __builtin_memcpy(&f, &v, 4); return f;
}
__device__ __forceinline__ unsigned short f2bf_u(float f) {
  __hip_bfloat16 h = __float2bfloat16(f); unsigned short u; __builtin_memcpy(&u, &h, 2); return u;
}
__device__ __forceinline__ float agload(const float* p) {
  return __hip_atomic_load(p, __ATOMIC_RELAXED, __HIP_MEMORY_SCOPE_AGENT);
}
__device__ __forceinline__ void agstore(float* p, float v) {
  __hip_atomic_store(p, v, __ATOMIC_RELAXED, __HIP_MEMORY_SCOPE_AGENT);
}
__device__ __forceinline__ void unpk(unsigned u, float& lo, float& hi) {
  unsigned l = u << 16, h = u & 0xffff0000u;
  __builtin_memcpy(&lo, &l, 4); __builtin_memcpy(&hi, &h, 4);
}
// Opaque-def pin: value becomes asm-produced -> compiler cannot rematerialize the
// originating global load; forces a live VGPR across the persistent loop.
__device__ __forceinline__ void pin_u(unsigned& x) { asm volatile("" : "+v"(x)); }

// ---------------- workspace layout (bytes) ----------------
constexpr size_t OFF_ATTNR = 0;
constexpr size_t SZ_ATTNR = (size_t)64 * 256 * 1024 * 2;           // 33,554,432
constexpr size_t OFF_ENCBF = OFF_ATTNR + SZ_ATTNR;                 // bf16 [b][te][d]
constexpr size_t SZ_ENCBF = (size_t)64 * 1024 * 256 * 2;
constexpr size_t OFF_PRE2 = OFF_ENCBF + SZ_ENCBF;                  // bf16 [64000][256]
constexpr size_t SZ_PRE2 = (size_t)64000 * 256 * 2;
constexpr size_t OFF_WG4 = OFF_PRE2 + SZ_PRE2;                     // f32 [4][64][256][4]
constexpr size_t SZ_W4 = (size_t)262144 * 4;
constexpr size_t OFF_WP4 = OFF_WG4 + SZ_W4;
constexpr size_t OFF_WHH4 = OFF_WP4 + SZ_W4;                       // f32 [4][16][1024][4]
constexpr size_t OFF_WDEC4 = OFF_WHH4 + SZ_W4;                     // f32 [4][16][256][4]
constexpr size_t SZ_WDEC4 = (size_t)65536 * 4;
constexpr size_t OFF_MELT = OFF_WDEC4 + SZ_WDEC4;                  // f32 [4][128][80]
constexpr size_t SZ_MELT = (size_t)4 * 128 * 80 * 4;
constexpr size_t OFF_STOPT = OFF_MELT + SZ_MELT;                   // f32 [4][128]
constexpr size_t SZ_STOPT = (size_t)4 * 128 * 4;
constexpr size_t OFF_BIASG = OFF_STOPT + SZ_STOPT;                 // f32 [4][256]
constexpr size_t SZ_BIASG = (size_t)4 * 256 * 4;
constexpr size_t OFF_EXCH = (OFF_BIASG + SZ_BIASG + 255) & ~(size_t)255;
constexpr size_t EXF_DEC = 0;                          // [2][64][4][256]
constexpr size_t EXN_DEC = (size_t)2 * 64 * 4 * 256;
constexpr size_t EXF_GH = EXF_DEC + EXN_DEC;           // [2][64][4][1024]
constexpr size_t EXN_GH = (size_t)2 * 64 * 4 * 1024;
constexpr size_t EXF_CTX = EXF_GH + EXN_GH;            // [64][4][256]
constexpr size_t EXN_CTX = (size_t)64 * 4 * 256;
constexpr size_t EXF_S = EXF_CTX + EXN_CTX;            // [64][16]
constexpr size_t EXN_S = 64 * 16;
constexpr size_t EXF_CTR = EXF_S + EXN_S;              // u32 [64][16]
constexpr size_t EXN_CTR = 64 * 16;
constexpr size_t EXCH_FLOATS = EXF_CTR + EXN_CTR;
constexpr size_t SZ_EXCH = EXCH_FLOATS * 4;
constexpr size_t WS_NEED = OFF_EXCH + SZ_EXCH;         // ~101.4 MiB

// ---------------- fp32 -> bf16 convert (enc) ----------------
__global__ __launch_bounds__(256) void conv_bf16(const float* __restrict__ in,
                                                 unsigned short* __restrict__ out, int n) {
  int i = (blockIdx.x * 256 + threadIdx.x) * 2;
  if (i < n) {
    float2 v = *(const float2*)(in + i);
    unsigned pair = (unsigned)f2bf_u(v.x) | ((unsigned)f2bf_u(v.y) << 16);
    *(unsigned*)(out + i) = pair;
  }
}

// ---------------- weight re-layout (fp32 packed-4) ----------------
__global__ __launch_bounds__(256) void prep_weights(
    const float* __restrict__ W_ih, const float* __restrict__ W_hh,
    const float* __restrict__ W_dec, const float* __restrict__ mel_W,
    const float* __restrict__ stop_W, const float* __restrict__ b_ih,
    const float* __restrict__ b_hh,
    float* __restrict__ Wg4, float* __restrict__ Wp4,
    float* __restrict__ Whh4, float* __restrict__ Wdec4,
    float* __restrict__ MelT, float* __restrict__ StopT, float* __restrict__ biasG) {
  int idx = blockIdx.x * 256 + threadIdx.x;
  if (idx < 262144) {
    int q = idx & 3, r = (idx >> 2) & 255, kq = (idx >> 10) & 63, s = idx >> 16;
    int grow = ((r >> 6) << 8) + s * 64 + (r & 63);
    Wg4[idx] = W_ih[(size_t)grow * 512 + 256 + kq * 4 + q];
    Wp4[idx] = W_ih[(size_t)grow * 512 + kq * 4 + q];
  } else if (idx < 524288) {
    int i = idx - 262144;
    int q = i & 3, rr = (i >> 2) & 1023, hq = (i >> 12) & 15, s = i >> 16;
    Whh4[i] = W_hh[(size_t)rr * 256 + s * 64 + hq * 4 + q];
  } else if (idx < 589824) {
    int i = idx - 524288;
    int q = i & 3, a = (i >> 2) & 255, hq = (i >> 10) & 15, s = (i >> 14) & 3;
    Wdec4[i] = W_dec[(size_t)a * 256 + s * 64 + hq * 4 + q];
  } else if (idx < 589824 + 40960) {
    int k = idx - 589824;
    int m = k % 80, r = k / 80;
    int cc = r & 127, s = r >> 7;
    int col = (cc < 64) ? (s * 64 + cc) : (256 + s * 64 + (cc - 64));
    MelT[k] = mel_W[(size_t)m * 512 + col];
  } else if (idx < 589824 + 40960 + 512) {
    int k = idx - (589824 + 40960);
    int cc = k & 127, s = k >> 7;
    int col = (cc < 64) ? (s * 64 + cc) : (256 + s * 64 + (cc - 64));
    StopT[k] = stop_W[col];
  } else if (idx < 589824 + 40960 + 512 + 1024) {
    int k = idx - (589824 + 40960 + 512);
    int j = k & 255, s = k >> 8;
    int row = ((j >> 6) << 8) + s * 64 + (j & 63);
    biasG[k] = b_ih[row] + b_hh[row];
  }
}

// ---------------- attn_enc GEMM -> reg-resident bf16 layout attnR ----------------
__global__ __launch_bounds__(256) void attn_gemm(const float* __restrict__ enc,
                                                 const float* __restrict__ W_enc,
                                                 const float* __restrict__ b_enc,
                                                 unsigned* __restrict__ attnR) {
  __shared__ unsigned short Alds[64 * 260];
  const int tid = threadIdx.x;
  const int row0 = blockIdx.x * 64;
  const int wv = tid >> 6, lane = tid & 63, nb = wv * 64;
  for (int idx = tid; idx < 64 * 256; idx += 256) {
    int r = idx >> 8, k = idx & 255;
    Alds[r * 260 + k] = f2bf_u(enc[(size_t)(row0 + r) * 256 + k]);
  }
  __syncthreads();
  float acc[64];
#pragma unroll
  for (int n = 0; n < 64; ++n) acc[n] = b_enc[nb + n];
  for (int k8 = 0; k8 < 256; k8 += 8) {
    ushort4 ua = *(const ushort4*)&Alds[lane * 260 + k8];
    ushort4 ub = *(const ushort4*)&Alds[lane * 260 + k8 + 4];
    float a0 = bf2f(ua.x), a1 = bf2f(ua.y), a2 = bf2f(ua.z), a3 = bf2f(ua.w);
    float a4 = bf2f(ub.x), a5 = bf2f(ub.y), a6 = bf2f(ub.z), a7 = bf2f(ub.w);
#pragma unroll
    for (int n = 0; n < 64; ++n) {
      const float4* wp = (const float4*)(W_enc + (size_t)(nb + n) * 256 + k8);
      float4 w0 = wp[0], w1 = wp[1];
      acc[n] = fmaf(a0, w0.x, acc[n]); acc[n] = fmaf(a1, w0.y, acc[n]);
      acc[n] = fmaf(a2, w0.z, acc[n]); acc[n] = fmaf(a3, w0.w, acc[n]);
      acc[n] = fmaf(a4, w1.x, acc[n]); acc[n] = fmaf(a5, w1.y, acc[n]);
      acc[n] = fmaf(a6, w1.z, acc[n]); acc[n] = fmaf(a7, w1.w, acc[n]);
    }
  }
  const float CE = 2.8853900817779268f;  // 2*log2(e)
  const int b = row0 >> 10;
  const int te_g = (row0 & 1023) + lane;
  const int sl = te_g >> 8, te_loc = te_g & 255;
#pragma unroll
  for (int n = 0; n < 64; n += 2) {
    int a = nb + n;
    unsigned pair = (unsigned)f2bf_u(acc[n] * CE) | ((unsigned)f2bf_u(acc[n + 1] * CE) << 16);
    size_t u4 = ((((size_t)(b * 4 + sl) * 4 + (a >> 6)) * 8 + ((a >> 3) & 7)) * 256 + te_loc);
    attnR[u4 * 4 + ((a & 7) >> 1)] = pair;
  }
}

// ---------------- fused prenet ----------------
__global__ __launch_bounds__(256) void prenet_fused(const float* __restrict__ tmel,
                                                    const float* __restrict__ W1,
                                                    const float* __restrict__ b1,
                                                    const float* __restrict__ W2,
                                                    const float* __restrict__ b2,
                                                    unsigned short* __restrict__ pre2) {
  __shared__ unsigned short Alds[64 * 260];
  const int tid = threadIdx.x;
  const int row0 = blockIdx.x * 64;
  const int wv = tid >> 6, lane = tid & 63, nb = wv * 64;
  for (int idx = tid; idx < 64 * 80; idx += 256) {
    int r = idx / 80, k = idx - r * 80;
    int R = row0 + r;
    float v = (R % 1000 != 0) ? tmel[(size_t)(R - 1) * NMEL + k] : 0.f;
    Alds[r * 260 + k] = f2bf_u(v);
  }
  __syncthreads();
  float acc[64];
#pragma unroll
  for (int n = 0; n < 64; ++n) acc[n] = b1[nb + n];
  for (int k8 = 0; k8 < 80; k8 += 8) {
    ushort4 ua = *(const ushort4*)&Alds[lane * 260 + k8];
    ushort4 ub = *(const ushort4*)&Alds[lane * 260 + k8 + 4];
    float a0 = bf2f(ua.x), a1 = bf2f(ua.y), a2 = bf2f(ua.z), a3 = bf2f(ua.w);
    float a4 = bf2f(ub.x), a5 = bf2f(ub.y), a6 = bf2f(ub.z), a7 = bf2f(ub.w);
#pragma unroll
    for (int n = 0; n < 64; ++n) {
      const float4* wp = (const float4*)(W1 + (size_t)(nb + n) * 80 + k8);
      float4 w0 = wp[0], w1 = wp[1];
      acc[n] = fmaf(a0, w0.x, acc[n]); acc[n] = fmaf(a1, w0.y, acc[n]);
      acc[n] = fmaf(a2, w0.z, acc[n]); acc[n] = fmaf(a3, w0.w, acc[n]);
      acc[n] = fmaf(a4, w1.x, acc[n]); acc[n] = fmaf(a5, w1.y, acc[n]);
      acc[n] = fmaf(a6, w1.z, acc[n]); acc[n] = fmaf(a7, w1.w, acc[n]);
    }
  }
  __syncthreads();
#pragma unroll
  for (int n = 0; n < 64; ++n) Alds[lane * 260 + nb + n] = f2bf_u(fmaxf(acc[n], 0.f));
  __syncthreads();
#pragma unroll
  for (int n = 0; n < 64; ++n) acc[n] = b2[nb + n];
  for (int k8 = 0; k8 < 256; k8 += 8) {
    ushort4 ua = *(const ushort4*)&Alds[lane * 260 + k8];
    ushort4 ub = *(const ushort4*)&Alds[lane * 260 + k8 + 4];
    float a0 = bf2f(ua.x), a1 = bf2f(ua.y), a2 = bf2f(ua.z), a3 = bf2f(ua.w);
    float a4 = bf2f(ub.x), a5 = bf2f(ub.y), a6 = bf2f(ub.z), a7 = bf2f(ub.w);
#pragma unroll
    for (int n = 0; n < 64; ++n) {
      const float4* wp = (const float4*)(W2 + (size_t)(nb + n) * 256 + k8);
      float4 w0 = wp[0], w1 = wp[1];
      acc[n] = fmaf(a0, w0.x, acc[n]); acc[n] = fmaf(a1, w0.y, acc[n]);
      acc[n] = fmaf(a2, w0.z, acc[n]); acc[n] = fmaf(a3, w0.w, acc[n]);
      acc[n] = fmaf(a4, w1.x, acc[n]); acc[n] = fmaf(a5, w1.y, acc[n]);
      acc[n] = fmaf(a6, w1.z, acc[n]); acc[n] = fmaf(a7, w1.w, acc[n]);
    }
  }
  __syncthreads();
#pragma unroll
  for (int n = 0; n < 64; ++n) Alds[lane * 260 + nb + n] = f2bf_u(fmaxf(acc[n], 0.f));
  __syncthreads();
  for (int idx = tid; idx < 64 * 128; idx += 256) {
    int r = idx >> 7, k2 = (idx & 127) * 2;
    unsigned pair = (unsigned)Alds[r * 260 + k2] | ((unsigned)Alds[r * 260 + k2 + 1] << 16);
    *(unsigned*)(pre2 + (size_t)(row0 + r) * 256 + k2) = pair;
  }
}

// ---------------- persistent decoder: attn_enc + enc pinned in VGPRs ----------------
// 256 WGs x 1024 threads; b = wg&63, s = wg>>6. __launch_bounds__(1024,4): 128-VGPR budget.
__global__ __launch_bounds__(1024, 4) void decoder_loop(
    const unsigned* __restrict__ attnR, const unsigned short* __restrict__ encbf,
    const unsigned short* __restrict__ pre2,
    const float* __restrict__ Wg4, const float* __restrict__ Wp4,
    const float* __restrict__ Whh4, const float* __restrict__ Wdec4,
    const float* __restrict__ MelT, const float* __restrict__ StopT,
    const float* __restrict__ biasG,
    float* exch, unsigned* ctr,
    const float* __restrict__ b_dec, const float* __restrict__ v_w,
    const float* __restrict__ v_b, const float* __restrict__ enc_mask,
    const float* __restrict__ mel_b, const float* __restrict__ stop_b,
    float* out) {
  __shared__ __align__(16) float scratch[4096];
  __shared__ __align__(16) float melT_lds[10240];
  __shared__ float stopT_lds[128];
  __shared__ __align__(16) float dec_lds[256];
  __shared__ __align__(16) float v2_lds[256];
  __shared__ __align__(16) float p_lds[256];
  __shared__ __align__(16) float ctx_lds[256];
  __shared__ __align__(16) float pre_lds[256];
  __shared__ float gates_lds[256];
  __shared__ float c_lds[64], h_lds[64];
  __shared__ float red_lds[16];
  __shared__ float sv_lds;

  const int tid = threadIdx.x;
  const int b = blockIdx.x & 63, s = blockIdx.x >> 6;
  const int t8 = tid & 255;
  const int chunk = tid >> 8;
  const int lane = tid & 63, wid = tid >> 6;
  const int w = tid >> 6;      // wave id 0..15
  const float CE = 2.8853900817779268f;   // 2*log2(e)
  const float L2E = 1.4426950408889634f;  // log2(e)

  if (tid < 256) {
    v2_lds[tid] = -2.f * v_w[tid];
    if (tid < 64) c_lds[tid] = 0.f;
    float sp = v_w[tid];
    for (int m = 32; m; m >>= 1) sp += __shfl_xor(sp, m);
    if (lane == 0) red_lds[wid] = sp;
  }
  for (int i = tid; i < 10240; i += 1024) melT_lds[i] = MelT[(size_t)s * 10240 + i];
  if (tid >= 512 && tid < 640) stopT_lds[tid - 512] = StopT[s * 128 + (tid - 512)];
  __syncthreads();
  if (tid == 0) sv_lds = red_lds[0] + red_lds[1] + red_lds[2] + red_lds[3];
  __syncthreads();
  const float Sv = sv_lds;
  const float vb = v_b[0];
  const float maskv = (tid < 256) ? enc_mask[b * 1024 + s * 256 + tid] : 0.f;
  const float bdec_r = (tid < 256) ? b_dec[tid] : 0.f;
  const float biasg_r = (tid < 256) ? biasG[s * 256 + tid] : 0.f;

  // ---- VGPR-resident slices, pinned against rematerialization ----
  uint4 attn_r4[8];
  {
    const uint4* apR = (const uint4*)attnR + (((size_t)(b * 4 + s) * 4 + chunk) * 8) * 256 + t8;
#pragma unroll
    for (int j = 0; j < 8; ++j) attn_r4[j] = apR[(size_t)j << 8];
  }
  uint2 enc_r2[16];
  {
    const uint2* epR = (const uint2*)encbf + ((size_t)(b * 1024 + s * 256 + w * 16)) * 64 + lane;
#pragma unroll
    for (int t = 0; t < 16; ++t) enc_r2[t] = epR[(size_t)t << 6];
  }
#pragma unroll
  for (int j = 0; j < 8; ++j) {
    pin_u(attn_r4[j].x); pin_u(attn_r4[j].y); pin_u(attn_r4[j].z); pin_u(attn_r4[j].w);
  }
#pragma unroll
  for (int t = 0; t < 16; ++t) { pin_u(enc_r2[t].x); pin_u(enc_r2[t].y); }

  const int grow = ((t8 >> 6) << 8) + s * 64 + (t8 & 63);
  const float4* wg4 = (const float4*)Wg4 + ((size_t)(s * 64 + chunk * 16)) * 256 + t8;
  const float4* wp4 = (const float4*)Wp4 + ((size_t)(s * 64 + chunk * 16)) * 256 + t8;
  const float4* wh4 = (const float4*)Whh4 + ((size_t)s) * 16384 + tid;
  const float4* wd4 = (const float4*)Wdec4 + ((size_t)(s * 16 + chunk * 4)) * 256 + t8;
  const unsigned short* pre2_b = pre2 + (size_t)b * 256000;

  float* decP = exch + EXF_DEC;
  float* ghP = exch + EXF_GH;
  float* ctxP = exch + EXF_CTX;
  float* sP = exch + EXF_S;
  unsigned* ctrb = ctr + b * 16;
  unsigned epoch = 0;

  for (int it = 0; it < 1000; ++it) {
    const int par = it & 1;
    const int pn = par ^ 1;
    float prefv = (tid < 256) ? bf2f(pre2_b[it * 256 + tid]) : 0.f;
    // ---- A0: gather decP partials ----
    scratch[tid] = agload(decP + ((size_t)(par * 64 + b)) * 1024 + tid);
    __syncthreads();
    if (tid < 256)
      dec_lds[tid] = (bdec_r + scratch[tid] + scratch[256 + tid] + scratch[512 + tid] +
                      scratch[768 + tid]) * CE;
    __syncthreads();
    // ---- A1: energy partial (attn from pinned VGPRs) ----
    {
      float acc = 0.f;
#pragma unroll
      for (int j = 0; j < 8; ++j) {
        uint4 u = attn_r4[j];
        int ab = chunk * 64 + j * 8;
        float4 d0 = *(const float4*)&dec_lds[ab];
        float4 d1 = *(const float4*)&dec_lds[ab + 4];
        float4 v0 = *(const float4*)&v2_lds[ab];
        float4 v1 = *(const float4*)&v2_lds[ab + 4];
        float t0, t1, t2, t3, t4, t5, t6, t7;
        unpk(u.x, t0, t1); unpk(u.y, t2, t3); unpk(u.z, t4, t5); unpk(u.w, t6, t7);
        acc = fmaf(v0.x, __builtin_amdgcn_rcpf(1.f + __builtin_amdgcn_exp2f(t0 + d0.x)), acc);
        acc = fmaf(v0.y, __builtin_amdgcn_rcpf(1.f + __builtin_amdgcn_exp2f(t1 + d0.y)), acc);
        acc = fmaf(v0.z, __builtin_amdgcn_rcpf(1.f + __builtin_amdgcn_exp2f(t2 + d0.z)), acc);
        acc = fmaf(v0.w, __builtin_amdgcn_rcpf(1.f + __builtin_amdgcn_exp2f(t3 + d0.w)), acc);
        acc = fmaf(v1.x, __builtin_amdgcn_rcpf(1.f + __builtin_amdgcn_exp2f(t4 + d1.x)), acc);
        acc = fmaf(v1.y, __builtin_amdgcn_rcpf(1.f + __builtin_amdgcn_exp2f(t5 + d1.y)), acc);
        acc = fmaf(v1.z, __builtin_amdgcn_rcpf(1.f + __builtin_amdgcn_exp2f(t6 + d1.z)), acc);
        acc = fmaf(v1.w, __builtin_amdgcn_rcpf(1.f + __builtin_amdgcn_exp2f(t7 + d1.w)), acc);
      }
      scratch[tid] = acc;
    }
    __syncthreads();
    // ---- A2: softmax numerator + slice sum ----
    if (tid < 256) {
      float e = Sv + vb + scratch[t8] + scratch[256 + t8] + scratch[512 + t8] + scratch[768 + t8];
      float p = (maskv != 0.f) ? __builtin_amdgcn_exp2f(e * L2E) : 0.f;
      p_lds[t8] = p;
      float sp = p;
      for (int m = 32; m; m >>= 1) sp += __shfl_xor(sp, m);
      if (lane == 0) red_lds[wid] = sp;
    }
    __syncthreads();
    // ---- B: context partials (enc from pinned VGPRs) ----
    {
      float c0 = 0, c1 = 0, c2 = 0, c3 = 0;
#pragma unroll
      for (int t = 0; t < 16; ++t) {
        float pv = p_lds[w * 16 + t];
        float e0, e1, e2, e3;
        unpk(enc_r2[t].x, e0, e1);
        unpk(enc_r2[t].y, e2, e3);
        c0 = fmaf(pv, e0, c0); c1 = fmaf(pv, e1, c1);
        c2 = fmaf(pv, e2, c2); c3 = fmaf(pv, e3, c3);
      }
      float* cb = &scratch[w * 256 + lane * 4];
      cb[0] = c0; cb[1] = c1; cb[2] = c2; cb[3] = c3;
      if (tid < 256) pre_lds[tid] = prefv;
    }
    __syncthreads();
    // ---- B2: reduce 16 waves -> publish ----
    if (tid < 256) {
      float cp = 0.f;
#pragma unroll
      for (int ww = 0; ww < 16; ++ww) cp += scratch[ww * 256 + t8];
      agstore(ctxP + ((size_t)b * 4 + s) * 256 + t8, cp);
    }
    if (tid == 0)
      agstore(sP + b * 16 + s, red_lds[0] + red_lds[1] + red_lds[2] + red_lds[3]);
    // ================= barrier 1 =================
    __threadfence();
    __syncthreads();
    if (tid == 0) {
      ++epoch;
      __hip_atomic_fetch_add(ctrb, 1u, __ATOMIC_RELEASE, __HIP_MEMORY_SCOPE_AGENT);
      while (__hip_atomic_load(ctrb, __ATOMIC_ACQUIRE, __HIP_MEMORY_SCOPE_AGENT) < 4u * epoch)
        __builtin_amdgcn_s_sleep(1);
    }
    __syncthreads();
    // ---- C: final normalized context ----
    scratch[tid] = agload(ctxP + ((size_t)b * 4 + chunk) * 256 + t8);
    if (tid < 4) red_lds[8 + tid] = agload(sP + b * 16 + tid);
    __syncthreads();
    if (tid < 256) {
      float rS = 1.f / (red_lds[8] + red_lds[9] + red_lds[10] + red_lds[11]);
      ctx_lds[t8] = (scratch[t8] + scratch[256 + t8] + scratch[512 + t8] + scratch[768 + t8]) * rS;
    }
    __syncthreads();
    // ---- D: gate partials (fp32 weights from L2) ----
    {
      float g = agload(ghP + ((size_t)(par * 64 + b)) * 4096 + chunk * 1024 + grow);
#pragma unroll 8
      for (int i = 0; i < 16; ++i) {
        float4 wv = wg4[(size_t)i << 8];
        float4 qv = wp4[(size_t)i << 8];
        int kb = chunk * 64 + i * 4;
        float4 x = *(const float4*)&ctx_lds[kb];
        float4 y = *(const float4*)&pre_lds[kb];
        g = fmaf(wv.x, x.x, g); g = fmaf(wv.y, x.y, g);
        g = fmaf(wv.z, x.z, g); g = fmaf(wv.w, x.w, g);
        g = fmaf(qv.x, y.x, g); g = fmaf(qv.y, y.y, g);
        g = fmaf(qv.z, y.z, g); g = fmaf(qv.w, y.w, g);
      }
      scratch[tid] = g;
    }
    __syncthreads();
    if (tid < 256)
      gates_lds[t8] = biasg_r + scratch[t8] + scratch[256 + t8] + scratch[512 + t8] +
                      scratch[768 + t8];
    __syncthreads();
    // ---- E: LSTM pointwise ----
    if (tid < 64) {
      float ii = gates_lds[tid], ff = gates_lds[64 + tid];
      float gg = gates_lds[128 + tid], oo = gates_lds[192 + tid];
      float c = c_lds[tid];
      float si = __builtin_amdgcn_rcpf(1.f + __builtin_amdgcn_exp2f(-ii * L2E));
      float sf = __builtin_amdgcn_rcpf(1.f + __builtin_amdgcn_exp2f(-ff * L2E));
      float so = __builtin_amdgcn_rcpf(1.f + __builtin_amdgcn_exp2f(-oo * L2E));
      float tg2 = 1.f - 2.f * __builtin_amdgcn_rcpf(1.f + __builtin_amdgcn_exp2f(gg * CE));
      float cn = sf * c + si * tg2;
      float tc = 1.f - 2.f * __builtin_amdgcn_rcpf(1.f + __builtin_amdgcn_exp2f(cn * CE));
      c_lds[tid] = cn;
      h_lds[tid] = so * tc;
    }
    __syncthreads();
    // ---- F: mel head + stop partial ----
    if (tid < 80) {
      float a = (s == 0) ? mel_b[tid] : 0.f;
#pragma unroll 8
      for (int cc = 0; cc < 128; ++cc) {
        float xv = (cc < 64) ? h_lds[cc] : ctx_lds[s * 64 + (cc - 64)];
        a = fmaf(melT_lds[cc * 80 + tid], xv, a);
      }
      atomicAdd(&out[(size_t)b * 80000 + it * 80 + tid], a);
    }
    if (tid >= 512 && tid < 640) {
      int cc = tid - 512;
      float xv = (cc < 64) ? h_lds[cc] : ctx_lds[s * 64 + (cc - 64)];
      float sv2 = stopT_lds[cc] * xv;
      for (int m = 32; m; m >>= 1) sv2 += __shfl_xor(sv2, m);
      if (lane == 0) red_lds[12 + ((tid - 512) >> 6)] = sv2;
    }
    // ---- G1/G2: next-step partials ----
    {
      float gd = 0.f;
#pragma unroll
      for (int i = 0; i < 4; ++i) {
        float4 wv = wd4[(size_t)i << 8];
        int hb = chunk * 16 + i * 4;
        gd = fmaf(wv.x, h_lds[hb + 0], gd); gd = fmaf(wv.y, h_lds[hb + 1], gd);
        gd = fmaf(wv.z, h_lds[hb + 2], gd); gd = fmaf(wv.w, h_lds[hb + 3], gd);
      }
      float gh = 0.f;
#pragma unroll 8
      for (int hq = 0; hq < 16; ++hq) {
        float4 wv = wh4[(size_t)hq << 10];
        gh = fmaf(wv.x, h_lds[hq * 4 + 0], gh); gh = fmaf(wv.y, h_lds[hq * 4 + 1], gh);
        gh = fmaf(wv.z, h_lds[hq * 4 + 2], gh); gh = fmaf(wv.w, h_lds[hq * 4 + 3], gh);
      }
      agstore(ghP + ((size_t)(pn * 64 + b) * 4 + s) * 1024 + tid, gh);
      scratch[tid] = gd;
    }
    __syncthreads();
    if (tid < 256)
      agstore(decP + ((size_t)(pn * 64 + b) * 4 + s) * 256 + t8,
              scratch[t8] + scratch[256 + t8] + scratch[512 + t8] + scratch[768 + t8]);
    if (tid == 0) {
      float st = (s == 0) ? stop_b[0] : 0.f;
      atomicAdd(&out[(size_t)5120000 + b * 1000 + it], st + red_lds[12] + red_lds[13]);
    }
    // ================= barrier 2 =================
    __threadfence();
    __syncthreads();
    if (tid == 0) {
      ++epoch;
      __hip_atomic_fetch_add(ctrb, 1u, __ATOMIC_RELEASE, __HIP_MEMORY_SCOPE_AGENT);
      while (__hip_atomic_load(ctrb, __ATOMIC_ACQUIRE, __HIP_MEMORY_SCOPE_AGENT) < 4u * epoch)
        __builtin_amdgcn_s_sleep(1);
    }
    __syncthreads();
  }
}

extern "C" void kernel_launch(void* const* d_in, const int* in_sizes, int n_in,
                              void* d_out, int out_size, void* d_ws, size_t ws_size,
                              hipStream_t stream) {
  const float* enc = (const float*)d_in[0];
  const float* tmel = (const float*)d_in[1];
  const float* W_enc = (const float*)d_in[2];
  const float* b_enc = (const float*)d_in[3];
  const float* W_dec = (const float*)d_in[4];
  const float* b_dec = (const float*)d_in[5];
  const float* v_w = (const float*)d_in[6];
  const float* v_b = (const float*)d_in[7];
  const float* pW1 = (const float*)d_in[8];
  const float* pb1 = (const float*)d_in[9];
  const float* pW2 = (const float*)d_in[10];
  const float* pb2 = (const float*)d_in[11];
  const float* W_ih = (const float*)d_in[12];
  const float* W_hh = (const float*)d_in[13];
  const float* b_ih = (const float*)d_in[14];
  const float* b_hh = (const float*)d_in[15];
  const float* mel_W = (const float*)d_in[16];
  const float* mel_b = (const float*)d_in[17];
  const float* stop_W = (const float*)d_in[18];
  const float* stop_b = (const float*)d_in[19];
  const float* emask = (const float*)d_in[20];

  if (ws_size < WS_NEED) return;  // fail-visible rather than corrupt

  char* ws = (char*)d_ws;
  unsigned* attnR = (unsigned*)(ws + OFF_ATTNR);
  unsigned short* encbf = (unsigned short*)(ws + OFF_ENCBF);
  unsigned short* pre2 = (unsigned short*)(ws + OFF_PRE2);
  float* Wg4 = (float*)(ws + OFF_WG4);
  float* Wp4 = (float*)(ws + OFF_WP4);
  float* Whh4 = (float*)(ws + OFF_WHH4);
  float* Wdec4 = (float*)(ws + OFF_WDEC4);
  float* MelT = (float*)(ws + OFF_MELT);
  float* StopT = (float*)(ws + OFF_STOPT);
  float* biasG = (float*)(ws + OFF_BIASG);
  float* exch = (float*)(ws + OFF_EXCH);
  unsigned* ctr = (unsigned*)(exch + EXF_CTR);

  hipMemsetAsync(exch, 0, SZ_EXCH, stream);
  hipMemsetAsync(d_out, 0, (size_t)out_size * 4, stream);

  conv_bf16<<<32768, 256, 0, stream>>>(enc, encbf, 64 * 1024 * 256);
  prep_weights<<<2470, 256, 0, stream>>>(W_ih, W_hh, W_dec, mel_W, stop_W, b_ih, b_hh,
                                         Wg4, Wp4, Whh4, Wdec4, MelT, StopT, biasG);
  attn_gemm<<<1024, 256, 0, stream>>>(enc, W_enc, b_enc, attnR);
  prenet_fused<<<1000, 256, 0, stream>>>(tmel, pW1, pb1, pW2, pb2, pre2);
  decoder_loop<<<256, 1024, 0, stream>>>(attnR, encbf, pre2, Wg4, Wp4, Whh4, Wdec4,
                                         MelT, StopT, biasG, exch, ctr, b_dec, v_w, v_b,
                                         emask, mel_b, stop_b, (float*)d_out);
}